// Round 2
// baseline (3559.745 us; speedup 1.0000x reference)
//
#include <hip/hip_runtime.h>
#include <hip/hip_bf16.h>

typedef __hip_bfloat16 bf16;
typedef __attribute__((ext_vector_type(8))) short short8;
typedef __attribute__((ext_vector_type(4))) float floatx4;

#define BM 128
#define BN 128
#define BK 32
#define LDK 40  // padded LDS row stride (elems): 80B -> 2-way bank aliasing only (free)

// ---------------------------------------------------------------------------
// Generic NT GEMM: C[m][n] = sum_k A[m][k] * Bt[n][k], fp32 acc.
// A/B may be fp32 (converted to bf16 during LDS staging) or bf16.
// One batch dim z with element strides sA/sB/sC.
// ---------------------------------------------------------------------------
template<bool OUT_BF16, bool A_F32, bool B_F32>
__global__ void __launch_bounds__(256) gemm_nt(
    const void* __restrict__ Av, const void* __restrict__ Bv, void* __restrict__ Cv,
    int M, int N, int K, int lda, int ldb, int ldc,
    long sA, long sB, long sC)
{
    __shared__ __align__(16) bf16 As[BM * LDK];
    __shared__ __align__(16) bf16 Bs[BN * LDK];

    int z = blockIdx.z;
    long aoff = (long)z * sA;
    long boff = (long)z * sB;
    long coff = (long)z * sC;

    int m0 = blockIdx.y * BM;
    int n0 = blockIdx.x * BN;
    int tid  = threadIdx.x;
    int lane = tid & 63;
    int wave = tid >> 6;
    int quad = lane >> 4;
    int l16  = lane & 15;
    int wm = (wave >> 1) * 64;   // wave's 64x64 sub-tile
    int wn = (wave & 1) * 64;

    floatx4 acc[4][4] = {};

    for (int k0 = 0; k0 < K; k0 += BK) {
        __syncthreads();
        // stage A and Bt tiles: 128 rows x 32 cols each, 8 elems per thread-load
#pragma unroll
        for (int i = 0; i < 2; i++) {
            int e = (tid + i * 256) * 8;
            int r = e >> 5;
            int c = e & 31;
            // ---- A side ----
            {
                int gm = m0 + r;
                if (A_F32) {
                    const float* Af = (const float*)Av;
                    float4 v0 = {0, 0, 0, 0}, v1 = {0, 0, 0, 0};
                    if (gm < M) {
                        const float* p = Af + aoff + (long)gm * lda + k0 + c;
                        v0 = *(const float4*)p;
                        v1 = *(const float4*)(p + 4);
                    }
                    bf16 t[8];
                    t[0] = __float2bfloat16(v0.x); t[1] = __float2bfloat16(v0.y);
                    t[2] = __float2bfloat16(v0.z); t[3] = __float2bfloat16(v0.w);
                    t[4] = __float2bfloat16(v1.x); t[5] = __float2bfloat16(v1.y);
                    t[6] = __float2bfloat16(v1.z); t[7] = __float2bfloat16(v1.w);
                    *(uint4*)(&As[r * LDK + c]) = *(const uint4*)t;
                } else {
                    const bf16* Ab = (const bf16*)Av;
                    uint4 va = {0, 0, 0, 0};
                    if (gm < M) va = *(const uint4*)(Ab + aoff + (long)gm * lda + k0 + c);
                    *(uint4*)(&As[r * LDK + c]) = va;
                }
            }
            // ---- B side ----
            {
                int gn = n0 + r;
                if (B_F32) {
                    const float* Bf = (const float*)Bv;
                    float4 v0 = {0, 0, 0, 0}, v1 = {0, 0, 0, 0};
                    if (gn < N) {
                        const float* p = Bf + boff + (long)gn * ldb + k0 + c;
                        v0 = *(const float4*)p;
                        v1 = *(const float4*)(p + 4);
                    }
                    bf16 t[8];
                    t[0] = __float2bfloat16(v0.x); t[1] = __float2bfloat16(v0.y);
                    t[2] = __float2bfloat16(v0.z); t[3] = __float2bfloat16(v0.w);
                    t[4] = __float2bfloat16(v1.x); t[5] = __float2bfloat16(v1.y);
                    t[6] = __float2bfloat16(v1.z); t[7] = __float2bfloat16(v1.w);
                    *(uint4*)(&Bs[r * LDK + c]) = *(const uint4*)t;
                } else {
                    const bf16* Bb = (const bf16*)Bv;
                    uint4 vb = {0, 0, 0, 0};
                    if (gn < N) vb = *(const uint4*)(Bb + boff + (long)gn * ldb + k0 + c);
                    *(uint4*)(&Bs[r * LDK + c]) = vb;
                }
            }
        }
        __syncthreads();

        short8 af[4], bfr[4];
#pragma unroll
        for (int i = 0; i < 4; i++)
            af[i] = *(const short8*)(&As[(wm + i * 16 + l16) * LDK + quad * 8]);
#pragma unroll
        for (int j = 0; j < 4; j++)
            bfr[j] = *(const short8*)(&Bs[(wn + j * 16 + l16) * LDK + quad * 8]);
#pragma unroll
        for (int i = 0; i < 4; i++)
#pragma unroll
            for (int j = 0; j < 4; j++)
                acc[i][j] = __builtin_amdgcn_mfma_f32_16x16x32_bf16(af[i], bfr[j], acc[i][j], 0, 0, 0);
    }

    // epilogue: C/D layout row = quad*4+reg, col = lane&15
#pragma unroll
    for (int i = 0; i < 4; i++) {
        int row = m0 + wm + i * 16 + quad * 4;
#pragma unroll
        for (int j = 0; j < 4; j++) {
            int col = n0 + wn + j * 16 + l16;
            if (col >= N) continue;
#pragma unroll
            for (int v = 0; v < 4; v++) {
                int r = row + v;
                if (r < M) {
                    float val = acc[i][j][v];
                    if (OUT_BF16)
                        ((bf16*)Cv)[coff + (long)r * ldc + col] = __float2bfloat16(val);
                    else
                        ((float*)Cv)[coff + (long)r * ldc + col] = val;
                }
            }
        }
    }
}

// ---------------------------------------------------------------------------
// Fused QK^T + online softmax for ONE batch. grid = (16 qtiles, 16 heads).
// One wave owns 16 q-rows. Two sweeps over the 64 K-tiles (16 rows each):
// sweep 1 -> running max/sum; sweep 2 -> recompute + write normalized bf16.
// Q,K: [H][4096 tok][64] pre-offset to this batch's tokens (stride 262144/head).
// W: [H][1024 q][1024 m].
// ---------------------------------------------------------------------------
__global__ void __launch_bounds__(256) attn_softmax(
    const bf16* __restrict__ Q, const bf16* __restrict__ Kb, bf16* __restrict__ Wts)
{
    __shared__ __align__(16) bf16 Ks[16 * 72];  // 72 = 64+8 pad

    int h = blockIdx.y;
    const bf16* Qbh = Q  + (long)h * 262144;
    const bf16* Kbh = Kb + (long)h * 262144;
    bf16* W = Wts + (long)h * 1048576;

    int tid  = threadIdx.x;
    int lane = tid & 63;
    int wave = tid >> 6;
    int quad = lane >> 4;
    int l16  = lane & 15;
    int q0 = blockIdx.x * 64 + wave * 16;

    short8 a0 = *(const short8*)(Qbh + (long)(q0 + l16) * 64 + quad * 8);
    short8 a1 = *(const short8*)(Qbh + (long)(q0 + l16) * 64 + 32 + quad * 8);

    const float scale = 0.125f;  // 1/sqrt(64)
    float mrun[4] = {-1e30f, -1e30f, -1e30f, -1e30f};
    float lrun[4] = {0.f, 0.f, 0.f, 0.f};

    for (int mt = 0; mt < 64; mt++) {
        __syncthreads();
        if (tid < 128) {
            int e = tid * 8, r = e >> 6, c = e & 63;
            *(uint4*)(&Ks[r * 72 + c]) = *(const uint4*)(Kbh + (long)(mt * 16 + r) * 64 + c);
        }
        __syncthreads();
        short8 b0 = *(const short8*)(&Ks[l16 * 72 + quad * 8]);
        short8 b1 = *(const short8*)(&Ks[l16 * 72 + 32 + quad * 8]);
        floatx4 acc = {0.f, 0.f, 0.f, 0.f};
        acc = __builtin_amdgcn_mfma_f32_16x16x32_bf16(a0, b0, acc, 0, 0, 0);
        acc = __builtin_amdgcn_mfma_f32_16x16x32_bf16(a1, b1, acc, 0, 0, 0);
#pragma unroll
        for (int v = 0; v < 4; v++) {
            float s = acc[v] * scale;
            float tm = s;
            tm = fmaxf(tm, __shfl_xor(tm, 1));
            tm = fmaxf(tm, __shfl_xor(tm, 2));
            tm = fmaxf(tm, __shfl_xor(tm, 4));
            tm = fmaxf(tm, __shfl_xor(tm, 8));
            float nm = fmaxf(mrun[v], tm);
            float p  = __expf(s - nm);
            float ts = p;
            ts += __shfl_xor(ts, 1);
            ts += __shfl_xor(ts, 2);
            ts += __shfl_xor(ts, 4);
            ts += __shfl_xor(ts, 8);
            lrun[v] = lrun[v] * __expf(mrun[v] - nm) + ts;
            mrun[v] = nm;
        }
    }

    float linv[4];
#pragma unroll
    for (int v = 0; v < 4; v++) linv[v] = 1.0f / lrun[v];

    for (int mt = 0; mt < 64; mt++) {
        __syncthreads();
        if (tid < 128) {
            int e = tid * 8, r = e >> 6, c = e & 63;
            *(uint4*)(&Ks[r * 72 + c]) = *(const uint4*)(Kbh + (long)(mt * 16 + r) * 64 + c);
        }
        __syncthreads();
        short8 b0 = *(const short8*)(&Ks[l16 * 72 + quad * 8]);
        short8 b1 = *(const short8*)(&Ks[l16 * 72 + 32 + quad * 8]);
        floatx4 acc = {0.f, 0.f, 0.f, 0.f};
        acc = __builtin_amdgcn_mfma_f32_16x16x32_bf16(a0, b0, acc, 0, 0, 0);
        acc = __builtin_amdgcn_mfma_f32_16x16x32_bf16(a1, b1, acc, 0, 0, 0);
#pragma unroll
        for (int v = 0; v < 4; v++) {
            float w = __expf(acc[v] * scale - mrun[v]) * linv[v];
            W[(long)(q0 + quad * 4 + v) * 1024 + mt * 16 + l16] = __float2bfloat16(w);
        }
    }
}

// ---------------------------------------------------------------------------
// fp32 -> bf16 cast (4 elems/thread)
// ---------------------------------------------------------------------------
__global__ void __launch_bounds__(256) cast_bf16_k(
    const float* __restrict__ in, bf16* __restrict__ out, int n4)
{
    int i = blockIdx.x * 256 + threadIdx.x;
    if (i >= n4) return;
    float4 v = ((const float4*)in)[i];
    bf16 t[4] = {__float2bfloat16(v.x), __float2bfloat16(v.y),
                 __float2bfloat16(v.z), __float2bfloat16(v.w)};
    ((uint2*)out)[i] = *(const uint2*)t;
}

// ---------------------------------------------------------------------------
// per-head transpose + cast: in [H][R][C] f32 -> out [H][C][R] bf16
// ---------------------------------------------------------------------------
__global__ void __launch_bounds__(256) transpose_cast(
    const float* __restrict__ in, bf16* __restrict__ out, int R, int C)
{
    __shared__ float t[32][33];
    int h = blockIdx.z;
    const float* inh = in + (long)h * R * C;
    bf16* outh = out + (long)h * R * C;
    int c0 = blockIdx.x * 32, r0 = blockIdx.y * 32;
    int tx = threadIdx.x, ty = threadIdx.y;
#pragma unroll
    for (int i = 0; i < 32; i += 8)
        t[ty + i][tx] = inh[(long)(r0 + ty + i) * C + c0 + tx];
    __syncthreads();
#pragma unroll
    for (int i = 0; i < 32; i += 8)
        outh[(long)(c0 + ty + i) * R + r0 + tx] = __float2bfloat16(t[tx][ty + i]);
}

// ---------------------------------------------------------------------------
// Launcher. Workspace layout (MB offsets):
//   wqt 0..2   [16][64][1024] bf16     wkt 2..4
//   wvt 4..36  [16][1024 v][1024 d]    wob 36..68 [1024][16384]
//   qb 68..76  [16][4096][64]          kb 76..84
//   vt_b 84..116  [16][1024 v][1024 m] (per-batch, reused)
//   wts_b 116..148 [16][1024 q][1024 m] (per-batch, reused)
//   att 148..: full mode [4][1024 v][16384 e] (128 MB, need 276 MB total)
//              lean mode [1024 v][16384 e] per-batch (32 MB, need 180 MB)
// Batch loop is serialized by stream order, so buffer reuse is safe.
// ---------------------------------------------------------------------------
extern "C" void kernel_launch(void* const* d_in, const int* in_sizes, int n_in,
                              void* d_out, int out_size, void* d_ws, size_t ws_size,
                              hipStream_t stream) {
    const float* query = (const float*)d_in[0];
    const float* key   = (const float*)d_in[1];
    const float* value = (const float*)d_in[2];
    const float* w_q   = (const float*)d_in[3];
    const float* w_k   = (const float*)d_in[4];
    const float* w_v   = (const float*)d_in[5];
    const float* w_o   = (const float*)d_in[6];
    float* out = (float*)d_out;

    char* ws = (char*)d_ws;
    const size_t MB = (size_t)1 << 20;
    bf16* wqt   = (bf16*)(ws + 0 * MB);
    bf16* wkt   = (bf16*)(ws + 2 * MB);
    bf16* wvt   = (bf16*)(ws + 4 * MB);
    bf16* wob   = (bf16*)(ws + 36 * MB);
    bf16* qb    = (bf16*)(ws + 68 * MB);
    bf16* kb    = (bf16*)(ws + 76 * MB);
    bf16* vt_b  = (bf16*)(ws + 84 * MB);
    bf16* wts_b = (bf16*)(ws + 116 * MB);
    bf16* att   = (bf16*)(ws + 148 * MB);
    bool full = ws_size >= 280 * MB;   // full att for all 4 batches?

    // weight prep (once per call)
    transpose_cast<<<dim3(2, 32, 16),  dim3(32, 8), 0, stream>>>(w_q, wqt, 1024, 64);
    transpose_cast<<<dim3(2, 32, 16),  dim3(32, 8), 0, stream>>>(w_k, wkt, 1024, 64);
    transpose_cast<<<dim3(32, 32, 16), dim3(32, 8), 0, stream>>>(w_v, wvt, 1024, 1024);
    cast_bf16_k<<<16384, 256, 0, stream>>>(w_o, wob, 1024 * 16384 / 4);

    // Q/K projections: per head h, qb[h][tok][dk] = X[tok][d] . Wt[h][dk][d]^T
    gemm_nt<true, true, false><<<dim3(1, 32, 16), 256, 0, stream>>>(
        query, wqt, qb, 4096, 64, 1024, 1024, 1024, 64, 0L, 65536L, 262144L);
    gemm_nt<true, true, false><<<dim3(1, 32, 16), 256, 0, stream>>>(
        key, wkt, kb, 4096, 64, 1024, 1024, 1024, 64, 0L, 65536L, 262144L);

    for (int b = 0; b < 4; b++) {
        // V^T proj: vt_b[h][v][m] = Wvt[h][v][d] . value_b[m][d]^T
        gemm_nt<true, false, true><<<dim3(8, 8, 16), 256, 0, stream>>>(
            wvt, value + (long)b * 1048576, vt_b,
            1024, 1024, 1024, 1024, 1024, 1024, 1048576L, 0L, 1048576L);

        // QK^T + softmax -> wts_b[h][q][m]
        attn_softmax<<<dim3(16, 16), 256, 0, stream>>>(
            qb + (long)b * 65536, kb + (long)b * 65536, wts_b);

        // PV^T: att[b][v][h*1024+q] = vt_b[h][v][m] . wts_b[h][q][m]^T
        bf16* att_b = full ? att + (long)b * 16777216 : att;
        gemm_nt<true, false, false><<<dim3(8, 8, 16), 256, 0, stream>>>(
            vt_b, wts_b, att_b,
            1024, 1024, 1024, 1024, 1024, 16384, 1048576L, 1048576L, 1024L);

        if (!full) {
            // final per batch: out[b][d][v] = wo[d][e] . att[v][e]^T
            gemm_nt<false, false, false><<<dim3(8, 8, 1), 256, 0, stream>>>(
                wob, att, out + (long)b * 1048576,
                1024, 1024, 16384, 16384, 16384, 1024, 0L, 0L, 0L);
        }
    }

    if (full) {
        // final, all batches: out[b][d][v] = wo[d][e] . att[b][v][e]^T
        gemm_nt<false, false, false><<<dim3(8, 8, 4), 256, 0, stream>>>(
            wob, att, out,
            1024, 1024, 16384, 16384, 16384, 1024, 0L, 16777216L, 1048576L);
    }

    (void)in_sizes; (void)n_in; (void)out_size; (void)ws_size;
}

// Round 4
// 1641.839 us; speedup vs baseline: 2.1681x; 2.1681x over previous
//
#include <hip/hip_runtime.h>
#include <hip/hip_bf16.h>

typedef __hip_bfloat16 bf16;
typedef __attribute__((ext_vector_type(8))) short short8;
typedef __attribute__((ext_vector_type(4))) float floatx4;

#define BM 128
#define BN 128
#define BK 32
#define LDK 40  // padded LDS row stride: 80B -> 2-way bank aliasing only (free)

// ---------------------------------------------------------------------------
// Generic NT GEMM (round-2 PROVEN): C[m][n] = sum_k A[m][k]*Bt[n][k], fp32 acc.
// A/B may be fp32 (converted to bf16 during LDS staging) or bf16.
// ---------------------------------------------------------------------------
template<bool OUT_BF16, bool A_F32, bool B_F32>
__global__ void __launch_bounds__(256) gemm_nt(
    const void* __restrict__ Av, const void* __restrict__ Bv, void* __restrict__ Cv,
    int M, int N, int K, int lda, int ldb, int ldc,
    long sA, long sB, long sC)
{
    __shared__ __align__(16) bf16 As[BM * LDK];
    __shared__ __align__(16) bf16 Bs[BN * LDK];

    int z = blockIdx.z;
    long aoff = (long)z * sA;
    long boff = (long)z * sB;
    long coff = (long)z * sC;

    int m0 = blockIdx.y * BM;
    int n0 = blockIdx.x * BN;
    int tid  = threadIdx.x;
    int lane = tid & 63;
    int wave = tid >> 6;
    int quad = lane >> 4;
    int l16  = lane & 15;
    int wm = (wave >> 1) * 64;
    int wn = (wave & 1) * 64;

    floatx4 acc[4][4] = {};

    for (int k0 = 0; k0 < K; k0 += BK) {
        __syncthreads();
#pragma unroll
        for (int i = 0; i < 2; i++) {
            int e = (tid + i * 256) * 8;
            int r = e >> 5;
            int c = e & 31;
            // ---- A side ----
            {
                int gm = m0 + r;
                if (A_F32) {
                    const float* Af = (const float*)Av;
                    float4 v0 = {0,0,0,0}, v1 = {0,0,0,0};
                    if (gm < M) {
                        const float* p = Af + aoff + (long)gm * lda + k0 + c;
                        v0 = *(const float4*)p;
                        v1 = *(const float4*)(p + 4);
                    }
                    bf16 t[8];
                    t[0]=__float2bfloat16(v0.x); t[1]=__float2bfloat16(v0.y);
                    t[2]=__float2bfloat16(v0.z); t[3]=__float2bfloat16(v0.w);
                    t[4]=__float2bfloat16(v1.x); t[5]=__float2bfloat16(v1.y);
                    t[6]=__float2bfloat16(v1.z); t[7]=__float2bfloat16(v1.w);
                    *(uint4*)(&As[r * LDK + c]) = *(const uint4*)t;
                } else {
                    const bf16* Ab = (const bf16*)Av;
                    uint4 va = {0,0,0,0};
                    if (gm < M) va = *(const uint4*)(Ab + aoff + (long)gm * lda + k0 + c);
                    *(uint4*)(&As[r * LDK + c]) = va;
                }
            }
            // ---- B side ----
            {
                int gn = n0 + r;
                if (B_F32) {
                    const float* Bf = (const float*)Bv;
                    float4 v0 = {0,0,0,0}, v1 = {0,0,0,0};
                    if (gn < N) {
                        const float* p = Bf + boff + (long)gn * ldb + k0 + c;
                        v0 = *(const float4*)p;
                        v1 = *(const float4*)(p + 4);
                    }
                    bf16 t[8];
                    t[0]=__float2bfloat16(v0.x); t[1]=__float2bfloat16(v0.y);
                    t[2]=__float2bfloat16(v0.z); t[3]=__float2bfloat16(v0.w);
                    t[4]=__float2bfloat16(v1.x); t[5]=__float2bfloat16(v1.y);
                    t[6]=__float2bfloat16(v1.z); t[7]=__float2bfloat16(v1.w);
                    *(uint4*)(&Bs[r * LDK + c]) = *(const uint4*)t;
                } else {
                    const bf16* Bb = (const bf16*)Bv;
                    uint4 vb = {0,0,0,0};
                    if (gn < N) vb = *(const uint4*)(Bb + boff + (long)gn * ldb + k0 + c);
                    *(uint4*)(&Bs[r * LDK + c]) = vb;
                }
            }
        }
        __syncthreads();

        short8 af[4], bfr[4];
#pragma unroll
        for (int i = 0; i < 4; i++)
            af[i] = *(const short8*)(&As[(wm + i * 16 + l16) * LDK + quad * 8]);
#pragma unroll
        for (int j = 0; j < 4; j++)
            bfr[j] = *(const short8*)(&Bs[(wn + j * 16 + l16) * LDK + quad * 8]);
#pragma unroll
        for (int i = 0; i < 4; i++)
#pragma unroll
            for (int j = 0; j < 4; j++)
                acc[i][j] = __builtin_amdgcn_mfma_f32_16x16x32_bf16(af[i], bfr[j], acc[i][j], 0, 0, 0);
    }

    // epilogue: C/D layout row = quad*4+reg, col = lane&15
#pragma unroll
    for (int i = 0; i < 4; i++) {
        int row = m0 + wm + i * 16 + quad * 4;
#pragma unroll
        for (int j = 0; j < 4; j++) {
            int col = n0 + wn + j * 16 + l16;
            if (col >= N) continue;
#pragma unroll
            for (int v = 0; v < 4; v++) {
                int r = row + v;
                if (r < M) {
                    float val = acc[i][j][v];
                    if (OUT_BF16)
                        ((bf16*)Cv)[coff + (long)r * ldc + col] = __float2bfloat16(val);
                    else
                        ((float*)Cv)[coff + (long)r * ldc + col] = val;
                }
            }
        }
    }
}

// ---------------------------------------------------------------------------
// Fused QK^T + online softmax, ONE batch. grid=(16 qtiles, 16 heads).
// Stages 64 K-rows/iter (all 256 threads load); per-lane online (m,l);
// one butterfly merge at end of sweep 1.
// Q,K: [H][4096 tok][64] (batch pre-offset). W: [H][1024 q][1024 m] bf16.
// ---------------------------------------------------------------------------
__global__ void __launch_bounds__(256) attn_softmax(
    const bf16* __restrict__ Q, const bf16* __restrict__ Kb, bf16* __restrict__ Wts)
{
    __shared__ __align__(16) bf16 Ks[64 * 72];

    int h = blockIdx.y;
    const bf16* Qbh = Q  + (long)h * 262144;
    const bf16* Kbh = Kb + (long)h * 262144;
    bf16* W = Wts + (long)h * 1048576;

    int tid  = threadIdx.x;
    int lane = tid & 63;
    int wave = tid >> 6;
    int quad = lane >> 4;
    int l16  = lane & 15;
    int q0 = blockIdx.x * 64 + wave * 16;

    short8 a0 = *(const short8*)(Qbh + (long)(q0 + l16) * 64 + quad * 8);
    short8 a1 = *(const short8*)(Qbh + (long)(q0 + l16) * 64 + 32 + quad * 8);

    int sr = tid >> 3;         // 0..31
    int sc = (tid & 7) * 8;    // 0..56, 16B aligned

    const float scale = 0.125f;
    float m_v[4] = {-1e30f, -1e30f, -1e30f, -1e30f};
    float l_v[4] = {0.f, 0.f, 0.f, 0.f};

    for (int t = 0; t < 16; t++) {
        __syncthreads();
        const bf16* src = Kbh + (long)(t * 64 + sr) * 64 + sc;
        *(uint4*)(&Ks[sr * 72 + sc])        = *(const uint4*)src;
        *(uint4*)(&Ks[(sr + 32) * 72 + sc]) = *(const uint4*)(src + 32 * 64);
        __syncthreads();
#pragma unroll
        for (int j = 0; j < 4; j++) {
            short8 b0 = *(const short8*)(&Ks[(j * 16 + l16) * 72 + quad * 8]);
            short8 b1 = *(const short8*)(&Ks[(j * 16 + l16) * 72 + 32 + quad * 8]);
            floatx4 acc = {0.f, 0.f, 0.f, 0.f};
            acc = __builtin_amdgcn_mfma_f32_16x16x32_bf16(a0, b0, acc, 0, 0, 0);
            acc = __builtin_amdgcn_mfma_f32_16x16x32_bf16(a1, b1, acc, 0, 0, 0);
#pragma unroll
            for (int v = 0; v < 4; v++) {
                float s  = acc[v] * scale;
                float nm = fmaxf(m_v[v], s);
                l_v[v] = l_v[v] * __expf(m_v[v] - nm) + __expf(s - nm);
                m_v[v] = nm;
            }
        }
    }

    // merge (m,l) across the 16 l16-lanes of each row
#pragma unroll
    for (int d = 1; d < 16; d <<= 1) {
#pragma unroll
        for (int v = 0; v < 4; v++) {
            float om = __shfl_xor(m_v[v], d);
            float ol = __shfl_xor(l_v[v], d);
            float nm = fmaxf(m_v[v], om);
            l_v[v] = l_v[v] * __expf(m_v[v] - nm) + ol * __expf(om - nm);
            m_v[v] = nm;
        }
    }
    float linv[4];
#pragma unroll
    for (int v = 0; v < 4; v++) linv[v] = 1.0f / l_v[v];

    for (int t = 0; t < 16; t++) {
        __syncthreads();
        const bf16* src = Kbh + (long)(t * 64 + sr) * 64 + sc;
        *(uint4*)(&Ks[sr * 72 + sc])        = *(const uint4*)src;
        *(uint4*)(&Ks[(sr + 32) * 72 + sc]) = *(const uint4*)(src + 32 * 64);
        __syncthreads();
#pragma unroll
        for (int j = 0; j < 4; j++) {
            short8 b0 = *(const short8*)(&Ks[(j * 16 + l16) * 72 + quad * 8]);
            short8 b1 = *(const short8*)(&Ks[(j * 16 + l16) * 72 + 32 + quad * 8]);
            floatx4 acc = {0.f, 0.f, 0.f, 0.f};
            acc = __builtin_amdgcn_mfma_f32_16x16x32_bf16(a0, b0, acc, 0, 0, 0);
            acc = __builtin_amdgcn_mfma_f32_16x16x32_bf16(a1, b1, acc, 0, 0, 0);
#pragma unroll
            for (int v = 0; v < 4; v++) {
                float w = __expf(acc[v] * scale - m_v[v]) * linv[v];
                W[(long)(q0 + quad * 4 + v) * 1024 + t * 64 + j * 16 + l16] = __float2bfloat16(w);
            }
        }
    }
}

// ---------------------------------------------------------------------------
__global__ void __launch_bounds__(256) cast_bf16_k(
    const float* __restrict__ in, bf16* __restrict__ out, int n4)
{
    int i = blockIdx.x * 256 + threadIdx.x;
    if (i >= n4) return;
    float4 v = ((const float4*)in)[i];
    bf16 t[4] = {__float2bfloat16(v.x), __float2bfloat16(v.y),
                 __float2bfloat16(v.z), __float2bfloat16(v.w)};
    ((uint2*)out)[i] = *(const uint2*)t;
}

__global__ void __launch_bounds__(256) transpose_cast(
    const float* __restrict__ in, bf16* __restrict__ out, int R, int C)
{
    __shared__ float t[32][33];
    int h = blockIdx.z;
    const float* inh = in + (long)h * R * C;
    bf16* outh = out + (long)h * R * C;
    int c0 = blockIdx.x * 32, r0 = blockIdx.y * 32;
    int tx = threadIdx.x, ty = threadIdx.y;
#pragma unroll
    for (int i = 0; i < 32; i += 8)
        t[ty + i][tx] = inh[(long)(r0 + ty + i) * C + c0 + tx];
    __syncthreads();
#pragma unroll
    for (int i = 0; i < 32; i += 8)
        outh[(long)(c0 + ty + i) * R + r0 + tx] = __float2bfloat16(t[tx][ty + i]);
}

// sum 16 fp32 partials of 1M elems each -> out (float4 per thread)
__global__ void __launch_bounds__(256) reduce16_k(
    const float* __restrict__ part, float* __restrict__ out)
{
    int i = blockIdx.x * 256 + threadIdx.x;   // float4 index, 262144 total
    float4 s = ((const float4*)part)[i];
#pragma unroll
    for (int c = 1; c < 16; c++) {
        float4 p = ((const float4*)part)[c * 262144 + i];
        s.x += p.x; s.y += p.y; s.z += p.z; s.w += p.w;
    }
    ((float4*)out)[i] = s;
}

// ---------------------------------------------------------------------------
// Workspace (MB, max 180 — proven in round 2):
//   wqt 0..2 | wkt 2..4 | wvt 4..36 | wob 36..68 | qb 68..76 | kb 76..84 |
//   vt_b 84..116 | wts_b 116..148 | att_b 148..180
//   out_part overlays 84..148 (vt_b/wts_b dead when final GEMM runs).
// ---------------------------------------------------------------------------
extern "C" void kernel_launch(void* const* d_in, const int* in_sizes, int n_in,
                              void* d_out, int out_size, void* d_ws, size_t ws_size,
                              hipStream_t stream) {
    const float* query = (const float*)d_in[0];
    const float* key   = (const float*)d_in[1];
    const float* value = (const float*)d_in[2];
    const float* w_q   = (const float*)d_in[3];
    const float* w_k   = (const float*)d_in[4];
    const float* w_v   = (const float*)d_in[5];
    const float* w_o   = (const float*)d_in[6];
    float* out = (float*)d_out;

    char* ws = (char*)d_ws;
    const size_t MB = (size_t)1 << 20;
    bf16* wqt      = (bf16*)(ws + 0 * MB);
    bf16* wkt      = (bf16*)(ws + 2 * MB);
    bf16* wvt      = (bf16*)(ws + 4 * MB);
    bf16* wob      = (bf16*)(ws + 36 * MB);
    bf16* qb       = (bf16*)(ws + 68 * MB);
    bf16* kb       = (bf16*)(ws + 76 * MB);
    bf16* vt_b     = (bf16*)(ws + 84 * MB);
    bf16* wts_b    = (bf16*)(ws + 116 * MB);
    bf16* att_b    = (bf16*)(ws + 148 * MB);
    float* out_part = (float*)(ws + 84 * MB);   // 64 MB overlay

    // weight prep
    transpose_cast<<<dim3(2, 32, 16),  dim3(32, 8), 0, stream>>>(w_q, wqt, 1024, 64);
    transpose_cast<<<dim3(2, 32, 16),  dim3(32, 8), 0, stream>>>(w_k, wkt, 1024, 64);
    transpose_cast<<<dim3(32, 32, 16), dim3(32, 8), 0, stream>>>(w_v, wvt, 1024, 1024);
    cast_bf16_k<<<16384, 256, 0, stream>>>(w_o, wob, 1024 * 16384 / 4);

    // Q/K projections: qb[h][tok][dk] = X[tok][d] . wqt[h][dk][d]^T
    gemm_nt<true, true, false><<<dim3(1, 32, 16), 256, 0, stream>>>(
        query, wqt, qb, 4096, 64, 1024, 1024, 1024, 64, 0L, 65536L, 262144L);
    gemm_nt<true, true, false><<<dim3(1, 32, 16), 256, 0, stream>>>(
        key, wkt, kb, 4096, 64, 1024, 1024, 1024, 64, 0L, 65536L, 262144L);

    for (int b = 0; b < 4; b++) {
        // V^T proj: vt_b[h][v][m] = wvt[h][v][d] . value_b[m][d]^T
        gemm_nt<true, false, true><<<dim3(8, 8, 16), 256, 0, stream>>>(
            wvt, value + (long)b * 1048576, vt_b,
            1024, 1024, 1024, 1024, 1024, 1024, 1048576L, 0L, 1048576L);

        // QK^T + softmax -> wts_b[h][q][m]
        attn_softmax<<<dim3(16, 16), 256, 0, stream>>>(
            qb + (long)b * 65536, kb + (long)b * 65536, wts_b);

        // PV^T: att_b[v][h*1024+q] = vt_b[h][v][m] . wts_b[h][q][m]^T
        gemm_nt<true, false, false><<<dim3(8, 8, 16), 256, 0, stream>>>(
            vt_b, wts_b, att_b,
            1024, 1024, 1024, 1024, 1024, 16384, 1048576L, 1048576L, 1024L);

        // final split-K over heads: out_part[h][d][v] = wo[d][h*1024+q] . att_b[v][h*1024+q]^T
        gemm_nt<false, false, false><<<dim3(8, 8, 16), 256, 0, stream>>>(
            wob, att_b, out_part,
            1024, 1024, 1024, 16384, 16384, 1024, 1024L, 1024L, 1048576L);

        // reduce 16 partials -> out[b]
        reduce16_k<<<1024, 256, 0, stream>>>(out_part, out + (long)b * 1048576);
    }

    (void)in_sizes; (void)n_in; (void)out_size; (void)ws_size;
}

// Round 5
// 1031.362 us; speedup vs baseline: 3.4515x; 1.5919x over previous
//
#include <hip/hip_runtime.h>
#include <hip/hip_bf16.h>

typedef __hip_bfloat16 bf16;
typedef __attribute__((ext_vector_type(8))) short short8;
typedef __attribute__((ext_vector_type(4))) float floatx4;

#define BK 64
#define LDK 72  // 64 + 8 pad: 2-way bank aliasing only (free per m136)

// ---------------------------------------------------------------------------
// Pipelined NT GEMM: C[m][n] = sum_k A[m][k]*Bt[n][k], fp32 acc, BK=64,
// 2-stage register prefetch (tile k+1 loads overlap tile k MFMAs).
// A/B fp32 (convert at LDS-store time) or bf16. Tiles 128x128, 4 waves.
// XCD swizzle when grid is (8,8,z%8==0): each XCD owns contiguous z-chunk.
// ---------------------------------------------------------------------------
template<bool OUT_BF16, bool A_F32, bool B_F32>
__global__ void __launch_bounds__(256) gemm_nt(
    const void* __restrict__ Av, const void* __restrict__ Bv, void* __restrict__ Cv,
    int M, int N, int K, int lda, int ldb, int ldc,
    long sA, long sB, long sC)
{
    __shared__ __align__(16) bf16 As[128 * LDK];
    __shared__ __align__(16) bf16 Bs[128 * LDK];

    int bx = blockIdx.x, by = blockIdx.y, bz = blockIdx.z;
    if (gridDim.x == 8 && gridDim.y == 8 && (gridDim.z & 7) == 0) {
        int hw  = bx + (by << 3) + (bz << 6);
        int xcd = hw & 7;
        int idx = hw >> 3;
        int zper = gridDim.z >> 3;
        bz = xcd * zper + (idx >> 6);
        int rem = idx & 63;
        by = rem >> 3;
        bx = rem & 7;
    }

    long aoff = (long)bz * sA;
    long boff = (long)bz * sB;
    long coff = (long)bz * sC;

    int m0 = by * 128;
    int n0 = bx * 128;
    int tid  = threadIdx.x;
    int lane = tid & 63;
    int wave = tid >> 6;
    int quad = lane >> 4;
    int l16  = lane & 15;
    int wm = (wave >> 1) * 64;
    int wn = (wave & 1) * 64;

    // staging geometry: thread covers rows sr+32s (s=0..3), cols [sc, sc+8)
    int sr = tid >> 3;
    int sc = (tid & 7) * 8;

    floatx4 acc[4][4] = {};

    // prefetch registers
    uint4  pa[4], pb[4];            // bf16 paths
    float4 pa0[4], pa1[4], pb0[4], pb1[4];  // f32 paths (convert at store)

    const int nt = K / BK;

    // ---- prefetch tile 0 ----
#pragma unroll
    for (int s = 0; s < 4; s++) {
        int r = sr + 32 * s;
        int gm = m0 + r;
        if (A_F32) {
            const float* p = (const float*)Av + aoff + (long)gm * lda + sc;
            if (gm < M) { pa0[s] = *(const float4*)p; pa1[s] = *(const float4*)(p + 4); }
            else { pa0[s] = {0,0,0,0}; pa1[s] = {0,0,0,0}; }
        } else {
            pa[s] = (gm < M) ? *(const uint4*)((const bf16*)Av + aoff + (long)gm * lda + sc)
                             : (uint4){0,0,0,0};
        }
        int gn = n0 + r;
        if (B_F32) {
            const float* p = (const float*)Bv + boff + (long)gn * ldb + sc;
            if (gn < N) { pb0[s] = *(const float4*)p; pb1[s] = *(const float4*)(p + 4); }
            else { pb0[s] = {0,0,0,0}; pb1[s] = {0,0,0,0}; }
        } else {
            pb[s] = (gn < N) ? *(const uint4*)((const bf16*)Bv + boff + (long)gn * ldb + sc)
                             : (uint4){0,0,0,0};
        }
    }

    for (int kt = 0; kt < nt; kt++) {
        __syncthreads();   // previous tile's LDS consumers done
        // ---- store prefetched tile into LDS ----
#pragma unroll
        for (int s = 0; s < 4; s++) {
            int r = sr + 32 * s;
            if (A_F32) {
                bf16 t[8];
                t[0]=__float2bfloat16(pa0[s].x); t[1]=__float2bfloat16(pa0[s].y);
                t[2]=__float2bfloat16(pa0[s].z); t[3]=__float2bfloat16(pa0[s].w);
                t[4]=__float2bfloat16(pa1[s].x); t[5]=__float2bfloat16(pa1[s].y);
                t[6]=__float2bfloat16(pa1[s].z); t[7]=__float2bfloat16(pa1[s].w);
                *(uint4*)(&As[r * LDK + sc]) = *(const uint4*)t;
            } else {
                *(uint4*)(&As[r * LDK + sc]) = pa[s];
            }
            if (B_F32) {
                bf16 t[8];
                t[0]=__float2bfloat16(pb0[s].x); t[1]=__float2bfloat16(pb0[s].y);
                t[2]=__float2bfloat16(pb0[s].z); t[3]=__float2bfloat16(pb0[s].w);
                t[4]=__float2bfloat16(pb1[s].x); t[5]=__float2bfloat16(pb1[s].y);
                t[6]=__float2bfloat16(pb1[s].z); t[7]=__float2bfloat16(pb1[s].w);
                *(uint4*)(&Bs[r * LDK + sc]) = *(const uint4*)t;
            } else {
                *(uint4*)(&Bs[r * LDK + sc]) = pb[s];
            }
        }
        __syncthreads();

        // ---- prefetch tile kt+1 (loads overlap the MFMAs below) ----
        if (kt + 1 < nt) {
            int k0 = (kt + 1) * BK;
#pragma unroll
            for (int s = 0; s < 4; s++) {
                int r = sr + 32 * s;
                int gm = m0 + r;
                if (A_F32) {
                    const float* p = (const float*)Av + aoff + (long)gm * lda + k0 + sc;
                    if (gm < M) { pa0[s] = *(const float4*)p; pa1[s] = *(const float4*)(p + 4); }
                    else { pa0[s] = {0,0,0,0}; pa1[s] = {0,0,0,0}; }
                } else {
                    pa[s] = (gm < M) ? *(const uint4*)((const bf16*)Av + aoff + (long)gm * lda + k0 + sc)
                                     : (uint4){0,0,0,0};
                }
                int gn = n0 + r;
                if (B_F32) {
                    const float* p = (const float*)Bv + boff + (long)gn * ldb + k0 + sc;
                    if (gn < N) { pb0[s] = *(const float4*)p; pb1[s] = *(const float4*)(p + 4); }
                    else { pb0[s] = {0,0,0,0}; pb1[s] = {0,0,0,0}; }
                } else {
                    pb[s] = (gn < N) ? *(const uint4*)((const bf16*)Bv + boff + (long)gn * ldb + k0 + sc)
                                     : (uint4){0,0,0,0};
                }
            }
        }

        // ---- MFMA over the staged 64-deep tile (2 x k32 sub-steps) ----
#pragma unroll
        for (int ks = 0; ks < 2; ks++) {
            short8 af[4], bfr[4];
#pragma unroll
            for (int i = 0; i < 4; i++)
                af[i] = *(const short8*)(&As[(wm + i * 16 + l16) * LDK + ks * 32 + quad * 8]);
#pragma unroll
            for (int j = 0; j < 4; j++)
                bfr[j] = *(const short8*)(&Bs[(wn + j * 16 + l16) * LDK + ks * 32 + quad * 8]);
#pragma unroll
            for (int i = 0; i < 4; i++)
#pragma unroll
                for (int j = 0; j < 4; j++)
                    acc[i][j] = __builtin_amdgcn_mfma_f32_16x16x32_bf16(af[i], bfr[j], acc[i][j], 0, 0, 0);
        }
    }

    // epilogue: C/D layout row = quad*4+reg, col = lane&15
#pragma unroll
    for (int i = 0; i < 4; i++) {
        int row = m0 + wm + i * 16 + quad * 4;
#pragma unroll
        for (int j = 0; j < 4; j++) {
            int col = n0 + wn + j * 16 + l16;
            if (col >= N) continue;
#pragma unroll
            for (int v = 0; v < 4; v++) {
                int r = row + v;
                if (r < M) {
                    float val = acc[i][j][v];
                    if (OUT_BF16)
                        ((bf16*)Cv)[coff + (long)r * ldc + col] = __float2bfloat16(val);
                    else
                        ((float*)Cv)[coff + (long)r * ldc + col] = val;
                }
            }
        }
    }
}

// ---------------------------------------------------------------------------
// Fused QK^T + online softmax, ONE batch (round-4 PROVEN, unchanged).
// ---------------------------------------------------------------------------
__global__ void __launch_bounds__(256) attn_softmax(
    const bf16* __restrict__ Q, const bf16* __restrict__ Kb, bf16* __restrict__ Wts)
{
    __shared__ __align__(16) bf16 Ks[64 * 72];

    int h = blockIdx.y;
    const bf16* Qbh = Q  + (long)h * 262144;
    const bf16* Kbh = Kb + (long)h * 262144;
    bf16* W = Wts + (long)h * 1048576;

    int tid  = threadIdx.x;
    int lane = tid & 63;
    int wave = tid >> 6;
    int quad = lane >> 4;
    int l16  = lane & 15;
    int q0 = blockIdx.x * 64 + wave * 16;

    short8 a0 = *(const short8*)(Qbh + (long)(q0 + l16) * 64 + quad * 8);
    short8 a1 = *(const short8*)(Qbh + (long)(q0 + l16) * 64 + 32 + quad * 8);

    int sr = tid >> 3;
    int sc = (tid & 7) * 8;

    const float scale = 0.125f;
    float m_v[4] = {-1e30f, -1e30f, -1e30f, -1e30f};
    float l_v[4] = {0.f, 0.f, 0.f, 0.f};

    for (int t = 0; t < 16; t++) {
        __syncthreads();
        const bf16* src = Kbh + (long)(t * 64 + sr) * 64 + sc;
        *(uint4*)(&Ks[sr * 72 + sc])        = *(const uint4*)src;
        *(uint4*)(&Ks[(sr + 32) * 72 + sc]) = *(const uint4*)(src + 32 * 64);
        __syncthreads();
#pragma unroll
        for (int j = 0; j < 4; j++) {
            short8 b0 = *(const short8*)(&Ks[(j * 16 + l16) * 72 + quad * 8]);
            short8 b1 = *(const short8*)(&Ks[(j * 16 + l16) * 72 + 32 + quad * 8]);
            floatx4 acc = {0.f, 0.f, 0.f, 0.f};
            acc = __builtin_amdgcn_mfma_f32_16x16x32_bf16(a0, b0, acc, 0, 0, 0);
            acc = __builtin_amdgcn_mfma_f32_16x16x32_bf16(a1, b1, acc, 0, 0, 0);
#pragma unroll
            for (int v = 0; v < 4; v++) {
                float s  = acc[v] * scale;
                float nm = fmaxf(m_v[v], s);
                l_v[v] = l_v[v] * __expf(m_v[v] - nm) + __expf(s - nm);
                m_v[v] = nm;
            }
        }
    }

#pragma unroll
    for (int d = 1; d < 16; d <<= 1) {
#pragma unroll
        for (int v = 0; v < 4; v++) {
            float om = __shfl_xor(m_v[v], d);
            float ol = __shfl_xor(l_v[v], d);
            float nm = fmaxf(m_v[v], om);
            l_v[v] = l_v[v] * __expf(m_v[v] - nm) + ol * __expf(om - nm);
            m_v[v] = nm;
        }
    }
    float linv[4];
#pragma unroll
    for (int v = 0; v < 4; v++) linv[v] = 1.0f / l_v[v];

    for (int t = 0; t < 16; t++) {
        __syncthreads();
        const bf16* src = Kbh + (long)(t * 64 + sr) * 64 + sc;
        *(uint4*)(&Ks[sr * 72 + sc])        = *(const uint4*)src;
        *(uint4*)(&Ks[(sr + 32) * 72 + sc]) = *(const uint4*)(src + 32 * 64);
        __syncthreads();
#pragma unroll
        for (int j = 0; j < 4; j++) {
            short8 b0 = *(const short8*)(&Ks[(j * 16 + l16) * 72 + quad * 8]);
            short8 b1 = *(const short8*)(&Ks[(j * 16 + l16) * 72 + 32 + quad * 8]);
            floatx4 acc = {0.f, 0.f, 0.f, 0.f};
            acc = __builtin_amdgcn_mfma_f32_16x16x32_bf16(a0, b0, acc, 0, 0, 0);
            acc = __builtin_amdgcn_mfma_f32_16x16x32_bf16(a1, b1, acc, 0, 0, 0);
#pragma unroll
            for (int v = 0; v < 4; v++) {
                float w = __expf(acc[v] * scale - m_v[v]) * linv[v];
                W[(long)(q0 + quad * 4 + v) * 1024 + t * 64 + j * 16 + l16] = __float2bfloat16(w);
            }
        }
    }
}

// ---------------------------------------------------------------------------
__global__ void __launch_bounds__(256) cast_bf16_k(
    const float* __restrict__ in, bf16* __restrict__ out, int n4)
{
    int i = blockIdx.x * 256 + threadIdx.x;
    if (i >= n4) return;
    float4 v = ((const float4*)in)[i];
    bf16 t[4] = {__float2bfloat16(v.x), __float2bfloat16(v.y),
                 __float2bfloat16(v.z), __float2bfloat16(v.w)};
    ((uint2*)out)[i] = *(const uint2*)t;
}

__global__ void __launch_bounds__(256) transpose_cast(
    const float* __restrict__ in, bf16* __restrict__ out, int R, int C)
{
    __shared__ float t[32][33];
    int h = blockIdx.z;
    const float* inh = in + (long)h * R * C;
    bf16* outh = out + (long)h * R * C;
    int c0 = blockIdx.x * 32, r0 = blockIdx.y * 32;
    int tx = threadIdx.x, ty = threadIdx.y;
#pragma unroll
    for (int i = 0; i < 32; i += 8)
        t[ty + i][tx] = inh[(long)(r0 + ty + i) * C + c0 + tx];
    __syncthreads();
#pragma unroll
    for (int i = 0; i < 32; i += 8)
        outh[(long)(c0 + ty + i) * R + r0 + tx] = __float2bfloat16(t[tx][ty + i]);
}

// sum 16 fp32 partials of 1M elems each -> out (float4 per thread)
__global__ void __launch_bounds__(256) reduce16_k(
    const float* __restrict__ part, float* __restrict__ out)
{
    int i = blockIdx.x * 256 + threadIdx.x;
    float4 s = ((const float4*)part)[i];
#pragma unroll
    for (int c = 1; c < 16; c++) {
        float4 p = ((const float4*)part)[c * 262144 + i];
        s.x += p.x; s.y += p.y; s.z += p.z; s.w += p.w;
    }
    ((float4*)out)[i] = s;
}

// ---------------------------------------------------------------------------
// Workspace (MB, max 180 — proven):
//   wqt 0..2 | wkt 2..4 | wvt 4..36 | wob 36..68 | qb 68..76 | kb 76..84 |
//   vt_b 84..116 | wts_b 116..148 | att_b 148..180
//   out_part overlays 84..148 (vt_b/wts_b dead when final GEMM runs).
// ---------------------------------------------------------------------------
extern "C" void kernel_launch(void* const* d_in, const int* in_sizes, int n_in,
                              void* d_out, int out_size, void* d_ws, size_t ws_size,
                              hipStream_t stream) {
    const float* query = (const float*)d_in[0];
    const float* key   = (const float*)d_in[1];
    const float* value = (const float*)d_in[2];
    const float* w_q   = (const float*)d_in[3];
    const float* w_k   = (const float*)d_in[4];
    const float* w_v   = (const float*)d_in[5];
    const float* w_o   = (const float*)d_in[6];
    float* out = (float*)d_out;

    char* ws = (char*)d_ws;
    const size_t MB = (size_t)1 << 20;
    bf16* wqt      = (bf16*)(ws + 0 * MB);
    bf16* wkt      = (bf16*)(ws + 2 * MB);
    bf16* wvt      = (bf16*)(ws + 4 * MB);
    bf16* wob      = (bf16*)(ws + 36 * MB);
    bf16* qb       = (bf16*)(ws + 68 * MB);
    bf16* kb       = (bf16*)(ws + 76 * MB);
    bf16* vt_b     = (bf16*)(ws + 84 * MB);
    bf16* wts_b    = (bf16*)(ws + 116 * MB);
    bf16* att_b    = (bf16*)(ws + 148 * MB);
    float* out_part = (float*)(ws + 84 * MB);   // 64 MB overlay

    // weight prep
    transpose_cast<<<dim3(2, 32, 16),  dim3(32, 8), 0, stream>>>(w_q, wqt, 1024, 64);
    transpose_cast<<<dim3(2, 32, 16),  dim3(32, 8), 0, stream>>>(w_k, wkt, 1024, 64);
    transpose_cast<<<dim3(32, 32, 16), dim3(32, 8), 0, stream>>>(w_v, wvt, 1024, 1024);
    cast_bf16_k<<<16384, 256, 0, stream>>>(w_o, wob, 1024 * 16384 / 4);

    // Q/K projections: qb[h][tok][dk] = X[tok][d] . wqt[h][dk][d]^T
    gemm_nt<true, true, false><<<dim3(1, 32, 16), 256, 0, stream>>>(
        query, wqt, qb, 4096, 64, 1024, 1024, 1024, 64, 0L, 65536L, 262144L);
    gemm_nt<true, true, false><<<dim3(1, 32, 16), 256, 0, stream>>>(
        key, wkt, kb, 4096, 64, 1024, 1024, 1024, 64, 0L, 65536L, 262144L);

    for (int b = 0; b < 4; b++) {
        // V^T proj: vt_b[h][v][m] = wvt[h][v][d] . value_b[m][d]^T
        gemm_nt<true, false, true><<<dim3(8, 8, 16), 256, 0, stream>>>(
            wvt, value + (long)b * 1048576, vt_b,
            1024, 1024, 1024, 1024, 1024, 1024, 1048576L, 0L, 1048576L);

        // QK^T + softmax -> wts_b[h][q][m]
        attn_softmax<<<dim3(16, 16), 256, 0, stream>>>(
            qb + (long)b * 65536, kb + (long)b * 65536, wts_b);

        // PV^T: att_b[v][h*1024+q] = vt_b[h][v][m] . wts_b[h][q][m]^T
        gemm_nt<true, false, false><<<dim3(8, 8, 16), 256, 0, stream>>>(
            vt_b, wts_b, att_b,
            1024, 1024, 1024, 1024, 1024, 16384, 1048576L, 1048576L, 1024L);

        // final split-K over heads: out_part[h][d][v] = wo[d][h*1024+q] . att_b[v][h*1024+q]^T
        gemm_nt<false, false, false><<<dim3(8, 8, 16), 256, 0, stream>>>(
            wob, att_b, out_part,
            1024, 1024, 1024, 16384, 16384, 1024, 1024L, 1024L, 1048576L);

        // reduce 16 partials -> out[b]
        reduce16_k<<<1024, 256, 0, stream>>>(out_part, out + (long)b * 1048576);
    }

    (void)in_sizes; (void)n_in; (void)out_size; (void)ws_size;
}